// Round 6
// baseline (20003.448 us; speedup 1.0000x reference)
//
#include <hip/hip_runtime.h>
#include <math.h>
#include <stdint.h>

typedef _Float16 f16;
typedef _Float16 f16x8 __attribute__((ext_vector_type(8)));
typedef float f32x4 __attribute__((ext_vector_type(4)));

#define BATCH 1024
#define HD    512
#define TST   100
#define BUFSZ 49152   // 32KB A-tile + 16KB B-tile per kt-chunk

// s_getreg encoding: id | (offset<<6) | ((size-1)<<11); HW_REG_XCC_ID = 20 (gfx940+)
#define HWREG_XCC_ID (20 | (0 << 6) | (31 << 11))

// ---------------- shared-data access primitives ----------------
// COH=true : sc0 sc1 -> coherence point (cross-XCD safe, uncacheable)  [R5 proven]
// COH=false: sc0 only -> L1-bypass, served by local L2 (fresh within one XCD)
template<bool COH> __device__ __forceinline__ float4 sh_load_x4(const void* p) {
    float4 v;
    if (COH) asm volatile("global_load_dwordx4 %0, %1, off sc0 sc1" : "=v"(v) : "v"(p) : "memory");
    else     asm volatile("global_load_dwordx4 %0, %1, off sc0"     : "=v"(v) : "v"(p) : "memory");
    return v;
}
template<bool COH> __device__ __forceinline__ void sh_store_u32(uint32_t* p, uint32_t v) {
    if (COH) asm volatile("global_store_dword %0, %1, off sc0 sc1" :: "v"(p), "v"(v) : "memory");
    else     asm volatile("global_store_dword %0, %1, off sc0"     :: "v"(p), "v"(v) : "memory");
}
__device__ __forceinline__ int coh_load_i32(const int* p) {
    int v;
    asm volatile("global_load_dword %0, %1, off sc0 sc1\n\ts_waitcnt vmcnt(0)"
                 : "=v"(v) : "v"(p) : "memory");
    return v;
}
__device__ __forceinline__ void drain_vm() {
    asm volatile("s_waitcnt vmcnt(0)" ::: "memory");
    __builtin_amdgcn_sched_barrier(0);
}

// ---------------- setup kernels (unchanged, proven) ----------------
__global__ void split_w(const float* __restrict__ src0, int ksplit,
                        const float* __restrict__ src1, int NKT, f16* __restrict__ out)
{
    int c = blockIdx.x * 256 + threadIdx.x;
    int total = 16 * NKT * 2048;
    if (c >= total) return;
    int u = c & 2047;
    int t2 = c >> 11;          // mt*NKT + kt
    int kt = t2 % NKT;
    int mt = t2 / NKT;
    int line = u >> 4;
    int s = (u & 15) ^ (line & 15);   // content slot at this LDS position
    int plane = s >> 3, o = s & 7;
    int m = mt * 128 + line;
    int row = (m & 3) * HD + (m >> 2);    // original row g*512+hl
    int kb = kt * 64 + o * 8;
    f16 v[8];
    #pragma unroll
    for (int e = 0; e < 8; ++e) {
        int k = kb + e;
        float w = (k < ksplit) ? src0[(size_t)row * ksplit + k]
                               : src1[(size_t)row * HD + (k - ksplit)];
        float w32 = w * 32.0f;
        f16 hi = (f16)w32;
        v[e] = plane ? (f16)((w32 - (float)hi) * 2048.0f) : hi;
    }
    *(f16x8*)(out + (size_t)c * 8) = *(f16x8*)v;
}

__global__ void prep_b4(const float* __restrict__ b, float* __restrict__ bt) {
    int c = blockIdx.x * 256 + threadIdx.x;     // c = hl*4+g
    if (c < 2048) bt[c] = b[(c & 3) * HD + (c >> 2)];
}

__global__ void prep_wih4(const float* __restrict__ W, float* __restrict__ o) {
    int c = blockIdx.x * 256 + threadIdx.x;     // c = hl*16 + g*4 + j
    if (c < 8192) {
        int j = c & 3, g = (c >> 2) & 3, hl = c >> 4;
        o[c] = W[(size_t)(g * HD + hl) * 4 + j];
    }
}

// ---------------- cross-block sync (per nt-group, monotonic counters) ----------------
__device__ __forceinline__ void bump(int* c) {
    drain_vm();                        // all data stores (incl. asm sc stores) visible
    __syncthreads();
    if (threadIdx.x == 0)
        __hip_atomic_fetch_add(c, 1, __ATOMIC_RELAXED, __HIP_MEMORY_SCOPE_AGENT);
}
__device__ __forceinline__ void waitge(int* c, int tgt) {
    if (threadIdx.x == 0) {
        while (coh_load_i32(c) < tgt)
            __builtin_amdgcn_s_sleep(1);
    }
    __syncthreads();
}

// ---------------- fused LSTM layer-step (R2-R5 core math) ----------------
template<int NKT, bool RANK4, bool COH>
__device__ __forceinline__ void layer_step(
    const f16* __restrict__ Wst, const f16* __restrict__ src1, const f16* __restrict__ src2,
    const float* __restrict__ wih4, const float* __restrict__ xin, int xstride,
    const float* __restrict__ bt4, float* __restrict__ cT, f16* __restrict__ hout,
    char* smem, int mt, int nt)
{
    const int tid = threadIdx.x;
    const int lane = tid & 63;
    const int wv = tid >> 6;            // wave 0..3
    const int wm = wv & 1, wn = wv >> 1;
    const int l15 = lane & 15, j = lane >> 4;
    const int n0 = nt * 64;

    const int q = (j ^ l15) << 4;
    int ALr[4], BLb[2];
    #pragma unroll
    for (int f = 0; f < 4; ++f) ALr[f] = (wm * 64 + f * 16 + l15) * 256;
    #pragma unroll
    for (int fn = 0; fn < 2; ++fn) BLb[fn] = 32768 + (wn * 32 + fn * 16 + l15) * 256;

    float4 ra[8], rb[4];

    auto issue = [&](int kt) {
        const float4* ga = (const float4*)(Wst + ((size_t)mt * NKT + kt) * 2048 * 8);
        #pragma unroll
        for (int i = 0; i < 8; ++i) ra[i] = ga[i * 256 + tid];      // weights: plain cached
        #pragma unroll
        for (int i = 0; i < 4; ++i) {
            int v = i * 256 + tid;
            int line = v >> 4;
            int s = (v & 15) ^ (line & 15);
            int ks = kt * 64 + (s & 7) * 8;
            const f16* sp = src1; int kl = ks;
            if (NKT == 16 && ks >= 512) { sp = src2; kl = ks - 512; }
            rb[i] = sh_load_x4<COH>(sp + (size_t)(n0 + line) * 1024 + (s >> 3) * 512 + kl);
        }
    };

    f32x4 accA[4][2] = {};
    f32x4 accB[4][2] = {};

    issue(0);
    for (int kt = 0; kt < NKT; ++kt) {
        char* buf = smem + (kt & 1) * BUFSZ;
        drain_vm();                      // prefetched loads landed
        #pragma unroll
        for (int i = 0; i < 8; ++i) *(float4*)(buf + (i * 256 + tid) * 16) = ra[i];
        #pragma unroll
        for (int i = 0; i < 4; ++i) *(float4*)(buf + 32768 + (i * 256 + tid) * 16) = rb[i];
        if (kt + 1 < NKT) issue(kt + 1);
        __syncthreads();
        #pragma unroll
        for (int i = 0; i < 2; ++i) {
            const int off = (i << 6) ^ q;
            f16x8 ah[4], al[4], bh[2], bl[2];
            #pragma unroll
            for (int f = 0; f < 4; ++f) {
                ah[f] = *(const f16x8*)(buf + ALr[f] + off);
                al[f] = *(const f16x8*)(buf + ALr[f] + (off ^ 0x80));
            }
            #pragma unroll
            for (int fn = 0; fn < 2; ++fn) {
                bh[fn] = *(const f16x8*)(buf + BLb[fn] + off);
                bl[fn] = *(const f16x8*)(buf + BLb[fn] + (off ^ 0x80));
            }
            #pragma unroll
            for (int f = 0; f < 4; ++f)
                #pragma unroll
                for (int fn = 0; fn < 2; ++fn) {
                    accA[f][fn] = __builtin_amdgcn_mfma_f32_16x16x32_f16(ah[f], bh[fn], accA[f][fn], 0, 0, 0);
                    accB[f][fn] = __builtin_amdgcn_mfma_f32_16x16x32_f16(al[f], bh[fn], accB[f][fn], 0, 0, 0);
                    accB[f][fn] = __builtin_amdgcn_mfma_f32_16x16x32_f16(ah[f], bl[fn], accB[f][fn], 0, 0, 0);
                }
        }
        __syncthreads();
    }

    // epilogue: cell update in registers (D regs r=0..3 are gates i,f,g,o of one hl)
    const float sA = 1.0f / 1024.0f;
    const float sB = 1.0f / (1024.0f * 2048.0f);

    float4 xv[2];
    if (RANK4) {
        #pragma unroll
        for (int fn = 0; fn < 2; ++fn) {
            const int n = n0 + wn * 32 + fn * 16 + l15;
            xv[fn] = sh_load_x4<COH>(xin + (size_t)n * xstride);
        }
        drain_vm();
    }

    uint32_t* htile = (uint32_t*)smem;   // buf0 region; safe: last compute used buf1
    #pragma unroll
    for (int f = 0; f < 4; ++f) {
        const int hl_loc = wm * 16 + f * 4 + j;
        const int hl = mt * 32 + hl_loc;
        const float4 bv = *(const float4*)(bt4 + hl * 4);
        #pragma unroll
        for (int fn = 0; fn < 2; ++fn) {
            const int n_loc = wn * 32 + fn * 16 + l15;
            const int n = n0 + n_loc;
            float g0 = accA[f][fn][0] * sA + accB[f][fn][0] * sB + bv.x;
            float g1 = accA[f][fn][1] * sA + accB[f][fn][1] * sB + bv.y;
            float g2 = accA[f][fn][2] * sA + accB[f][fn][2] * sB + bv.z;
            float g3 = accA[f][fn][3] * sA + accB[f][fn][3] * sB + bv.w;
            if (RANK4) {
                const float4* wr = (const float4*)(wih4 + hl * 16);
                const float4 x4 = xv[fn];
                g0 += wr[0].x * x4.x + wr[0].y * x4.y + wr[0].z * x4.z + wr[0].w * x4.w;
                g1 += wr[1].x * x4.x + wr[1].y * x4.y + wr[1].z * x4.z + wr[1].w * x4.w;
                g2 += wr[2].x * x4.x + wr[2].y * x4.y + wr[2].z * x4.z + wr[2].w * x4.w;
                g3 += wr[3].x * x4.x + wr[3].y * x4.y + wr[3].z * x4.z + wr[3].w * x4.w;
            }
            const size_t co = (size_t)hl * 1024 + n;   // c: block-private, plain cached
            const float cold = cT[co];
            const float si = 1.0f / (1.0f + expf(-g0));
            const float sf = 1.0f / (1.0f + expf(-g1));
            const float so = 1.0f / (1.0f + expf(-g3));
            const float cn = sf * cold + si * tanhf(g2);
            const float hn = so * tanhf(cn);
            cT[co] = cn;
            const float h32 = hn * 32.0f;
            const f16 hi = (f16)h32;
            const f16 lo = (f16)((h32 - (float)hi) * 2048.0f);
            uint32_t pk = ((uint32_t)__builtin_bit_cast(uint16_t, lo) << 16)
                        | (uint32_t)__builtin_bit_cast(uint16_t, hi);
            htile[n_loc * 33 + hl_loc] = pk;
        }
    }
    __syncthreads();
    // writeout: pack pairs of adjacent hidden cols -> u32 stores (sc per mode)
    uint32_t* h32out = (uint32_t*)hout;
    #pragma unroll
    for (int i = 0; i < 8; ++i) {
        int u = i * 256 + tid;              // 0..2047
        int n_loc = u >> 5;                 // 0..63
        int r = u & 31;
        int plane = r >> 4;                 // 0=hi, 1=lo
        int p = r & 15;                     // u32 pair index within tile
        uint32_t t0 = htile[n_loc * 33 + 2 * p];
        uint32_t t1 = htile[n_loc * 33 + 2 * p + 1];
        uint32_t w = plane ? ((t1 & 0xffff0000u) | (t0 >> 16))
                           : ((t1 << 16) | (t0 & 0xffffu));
        sh_store_u32<COH>(h32out + (size_t)(n0 + n_loc) * 512 + plane * 256 + mt * 16 + p, w);
    }
}

// ---------------- pred + softmax, 4 batch rows per block (wave w -> row w) ----------------
template<bool COH>
__device__ __forceinline__ void pred_step(
    const f16* __restrict__ h1, const float* __restrict__ Wp, const float* __restrict__ bp,
    float* __restrict__ outp, float* __restrict__ xfb, int t, int mt, int nt)
{
    const int lane = threadIdx.x & 63;
    const int wv = threadIdx.x >> 6;
    const int n = nt * 64 + mt * 4 + wv;
    const f16* hr = h1 + (size_t)n * 1024;
    const int k0 = lane * 8;
    float4 hv4 = sh_load_x4<COH>(hr + k0);
    float4 lv4 = sh_load_x4<COH>(hr + 512 + k0);
    drain_vm();
    f16x8 hv = __builtin_bit_cast(f16x8, hv4);
    f16x8 lv = __builtin_bit_cast(f16x8, lv4);
    float h[8];
    #pragma unroll
    for (int e = 0; e < 8; ++e)
        h[e] = (float)hv[e] * 0.03125f + (float)lv[e] * (1.0f / 65536.0f);
    float a[4] = {};
    #pragma unroll
    for (int g = 0; g < 4; ++g) {
        const float4 wa = *(const float4*)(Wp + g * HD + k0);
        const float4 wb = *(const float4*)(Wp + g * HD + k0 + 4);
        a[g] = h[0]*wa.x + h[1]*wa.y + h[2]*wa.z + h[3]*wa.w
             + h[4]*wb.x + h[5]*wb.y + h[6]*wb.z + h[7]*wb.w;
    }
    #pragma unroll
    for (int off = 32; off > 0; off >>= 1) {
        a[0] += __shfl_xor(a[0], off);
        a[1] += __shfl_xor(a[1], off);
        a[2] += __shfl_xor(a[2], off);
        a[3] += __shfl_xor(a[3], off);
    }
    if (lane == 0) {
        const float4 bv = *(const float4*)bp;
        float v0 = a[0] + bv.x, v1 = a[1] + bv.y, v2 = a[2] + bv.z, v3 = a[3] + bv.w;
        float* op = outp + (size_t)n * (TST * 4) + t * 4;
        op[0] = v0; op[1] = v1; op[2] = v2; op[3] = v3;   // out: host-read, plain
        float m = fmaxf(fmaxf(v0, v1), fmaxf(v2, v3));
        float e0 = expf(v0 - m), e1 = expf(v1 - m), e2 = expf(v2 - m), e3 = expf(v3 - m);
        float inv = 1.0f / (e0 + e1 + e2 + e3);
        uint32_t* xp = (uint32_t*)(xfb + n * 4);
        float s0 = e0 * inv, s1 = e1 * inv, s2 = e2 * inv, s3 = e3 * inv;
        sh_store_u32<COH>(xp + 0, __builtin_bit_cast(uint32_t, s0));
        sh_store_u32<COH>(xp + 1, __builtin_bit_cast(uint32_t, s1));
        sh_store_u32<COH>(xp + 2, __builtin_bit_cast(uint32_t, s2));
        sh_store_u32<COH>(xp + 3, __builtin_bit_cast(uint32_t, s3));
    }
}

// ---------------- persistent whole-network kernel ----------------
struct Params {
    const f16 *WE0, *WE1, *WD0, *WD1;
    const float *wih4E, *wih4D, *btE0, *btE1, *btD0, *btD1;
    const float *X, *Wp, *bp;
    f16 *h0a, *h0b, *h1a, *h1b;
    float *c0, *c1;
    float *xfb0, *xfb1;
    float *out;
    int *cnt0, *cnt1, *cntp;     // 16 groups x 32-int stride
    int *roleCnt;                // 8 per-XCD counters
    int *arrCnt;                 // global arrival counter
};

template<bool COH>
__device__ __forceinline__ void run_net(const Params& P, char* smem, int mt, int nt)
{
    int* c0f = P.cnt0 + nt * 32;
    int* c1f = P.cnt1 + nt * 32;
    int* cpf = P.cntp + nt * 32;
    f16* h0b_[2] = { P.h0a, P.h0b };
    f16* h1b_[2] = { P.h1a, P.h1b };
    float* xfb_[2] = { P.xfb0, P.xfb1 };

    for (int u = 0; u < 2 * TST; ++u) {
        const bool enc = (u < TST);
        const int t = enc ? u : u - TST;

        // ---- layer 0 ----
        waitge(c0f, 16 * u);               // h0(u-1) published by group (WAR-safe too)
        if (!enc) waitge(cpf, 16 * t);     // xfb(t-1) ready
        layer_step<8, true, COH>(enc ? P.WE0 : P.WD0,
                            h0b_[(u + 1) & 1], nullptr,
                            enc ? P.wih4E : P.wih4D,
                            enc ? (P.X + t * 4) : xfb_[(t + 1) & 1],
                            enc ? (TST * 4) : 4,
                            enc ? P.btE0 : P.btD0,
                            P.c0, h0b_[u & 1], smem, mt, nt);
        bump(c0f);

        // ---- layer 1 ----
        waitge(c0f, 16 * (u + 1));         // h0(u) ready
        waitge(c1f, 16 * u);               // h1(u-1) ready
        layer_step<16, false, COH>(enc ? P.WE1 : P.WD1,
                              h0b_[u & 1], h1b_[(u + 1) & 1],
                              nullptr, nullptr, 0,
                              enc ? P.btE1 : P.btD1,
                              P.c1, h1b_[u & 1], smem, mt, nt);
        bump(c1f);

        // ---- pred + softmax feedback (decoder only) ----
        if (!enc) {
            waitge(c1f, 16 * (u + 1));     // full h1(t) rows from group
            pred_step<COH>(h1b_[u & 1], P.Wp, P.bp, P.out, xfb_[t & 1], t, mt, nt);
            bump(cpf);
        }
    }
}

__launch_bounds__(256, 1) __global__ void lstm_persistent(Params P)
{
    __shared__ __align__(16) char smem[2 * BUFSZ];
    __shared__ int s_cfg[3];

    // ---- XCD-aware role assignment (1 block/CU -> 32 blocks/XCD expected) ----
    if (threadIdx.x == 0) {
        int xcc = __builtin_amdgcn_s_getreg(HWREG_XCC_ID) & 7;
        int myIdx = __hip_atomic_fetch_add(&P.roleCnt[xcc], 1,
                                           __ATOMIC_RELAXED, __HIP_MEMORY_SCOPE_AGENT);
        drain_vm();     // roleCnt RMW globally done before arrival publish
        __hip_atomic_fetch_add(P.arrCnt, 1, __ATOMIC_RELAXED, __HIP_MEMORY_SCOPE_AGENT);
        while (coh_load_i32(P.arrCnt) < 256)
            __builtin_amdgcn_s_sleep(8);
        int even = 1;
        #pragma unroll
        for (int x = 0; x < 8; ++x)
            even &= (coh_load_i32(&P.roleCnt[x]) == 32);
        int nt, mt;
        if (even) {                        // XCD-pure groups BY CONSTRUCTION
            nt = xcc * 2 + (myIdx >> 4);
            mt = myIdx & 15;
        } else {                           // fallback: R5 static mapping, coherent path
            int bx = blockIdx.x;
            mt = ((bx & 7) << 1) | ((bx >> 3) & 1);
            nt = (bx >> 3) >> 1;
        }
        s_cfg[0] = nt; s_cfg[1] = mt; s_cfg[2] = even;
    }
    __syncthreads();
    const int nt = s_cfg[0], mt = s_cfg[1];
    if (s_cfg[2]) run_net<false>(P, smem, mt, nt);   // pure: XCD-local L2 traffic
    else          run_net<true >(P, smem, mt, nt);   // mixed: coherent (R5 semantics)
}

// ---------------- host ----------------
extern "C" void kernel_launch(void* const* d_in, const int* in_sizes, int n_in,
                              void* d_out, int out_size, void* d_ws, size_t ws_size,
                              hipStream_t stream)
{
    const float* X     = (const float*)d_in[0];
    const float* eWih0 = (const float*)d_in[2];
    const float* eWhh0 = (const float*)d_in[3];
    const float* eb0   = (const float*)d_in[4];
    const float* eWih1 = (const float*)d_in[5];
    const float* eWhh1 = (const float*)d_in[6];
    const float* eb1   = (const float*)d_in[7];
    const float* dWih0 = (const float*)d_in[8];
    const float* dWhh0 = (const float*)d_in[9];
    const float* db0   = (const float*)d_in[10];
    const float* dWih1 = (const float*)d_in[11];
    const float* dWhh1 = (const float*)d_in[12];
    const float* db1   = (const float*)d_in[13];
    const float* Wp    = (const float*)d_in[14];
    const float* bp    = (const float*)d_in[15];

    char* ws = (char*)d_ws;
    size_t off = 0;
    auto alloc = [&](size_t bytes) { char* p = ws + off; off += (bytes + 255) & ~(size_t)255; return p; };
    f16* WE0 = (f16*)alloc((size_t)16 * 8  * 2048 * 16);
    f16* WE1 = (f16*)alloc((size_t)16 * 16 * 2048 * 16);
    f16* WD0 = (f16*)alloc((size_t)16 * 8  * 2048 * 16);
    f16* WD1 = (f16*)alloc((size_t)16 * 16 * 2048 * 16);
    float* wih4E = (float*)alloc(8192 * 4);
    float* wih4D = (float*)alloc(8192 * 4);
    float* btE0 = (float*)alloc(2048 * 4);
    float* btE1 = (float*)alloc(2048 * 4);
    float* btD0 = (float*)alloc(2048 * 4);
    float* btD1 = (float*)alloc(2048 * 4);
    f16* h0a = (f16*)alloc((size_t)BATCH * 1024 * 2);
    f16* h0b = (f16*)alloc((size_t)BATCH * 1024 * 2);
    f16* h1a = (f16*)alloc((size_t)BATCH * 1024 * 2);
    f16* h1b = (f16*)alloc((size_t)BATCH * 1024 * 2);
    float* c0  = (float*)alloc((size_t)HD * BATCH * 4);
    float* c1  = (float*)alloc((size_t)HD * BATCH * 4);
    float* xfb0 = (float*)alloc((size_t)BATCH * 4 * 4);
    float* xfb1 = (float*)alloc((size_t)BATCH * 4 * 4);
    int* cnt0 = (int*)alloc(16 * 32 * 4);
    int* cnt1 = (int*)alloc(16 * 32 * 4);
    int* cntp = (int*)alloc(16 * 32 * 4);
    int* roleCnt = (int*)alloc(8 * 4);
    int* arrCnt  = (int*)alloc(4);
    if (off > ws_size) return;   // workspace too small -> loud failure

    // one-time (per-call) weight prep
    split_w<<<(16 * 8  * 2048) / 256, 256, 0, stream>>>(nullptr, 0,   eWhh0, 8,  WE0);
    split_w<<<(16 * 16 * 2048) / 256, 256, 0, stream>>>(eWih1, 512, eWhh1, 16, WE1);
    split_w<<<(16 * 8  * 2048) / 256, 256, 0, stream>>>(nullptr, 0,   dWhh0, 8,  WD0);
    split_w<<<(16 * 16 * 2048) / 256, 256, 0, stream>>>(dWih1, 512, dWhh1, 16, WD1);
    prep_wih4<<<32, 256, 0, stream>>>(eWih0, wih4E);
    prep_wih4<<<32, 256, 0, stream>>>(dWih0, wih4D);
    prep_b4<<<8, 256, 0, stream>>>(eb0, btE0);
    prep_b4<<<8, 256, 0, stream>>>(eb1, btE1);
    prep_b4<<<8, 256, 0, stream>>>(db0, btD0);
    prep_b4<<<8, 256, 0, stream>>>(db1, btD1);

    hipMemsetAsync(h0b, 0, (size_t)BATCH * 1024 * 2, stream);   // h0 parity-1 (read at u=0)
    hipMemsetAsync(h1b, 0, (size_t)BATCH * 1024 * 2, stream);   // h1 parity-1
    hipMemsetAsync(c0, 0, (size_t)HD * BATCH * 4, stream);
    hipMemsetAsync(c1, 0, (size_t)HD * BATCH * 4, stream);
    hipMemsetAsync(xfb1, 0, (size_t)BATCH * 4 * 4, stream);     // x feedback at dec t=0
    hipMemsetAsync(cnt0, 0, 16 * 32 * 4, stream);
    hipMemsetAsync(cnt1, 0, 16 * 32 * 4, stream);
    hipMemsetAsync(cntp, 0, 16 * 32 * 4, stream);
    hipMemsetAsync(roleCnt, 0, 8 * 4, stream);
    hipMemsetAsync(arrCnt, 0, 4, stream);

    Params P;
    P.WE0 = WE0; P.WE1 = WE1; P.WD0 = WD0; P.WD1 = WD1;
    P.wih4E = wih4E; P.wih4D = wih4D;
    P.btE0 = btE0; P.btE1 = btE1; P.btD0 = btD0; P.btD1 = btD1;
    P.X = X; P.Wp = Wp; P.bp = bp;
    P.h0a = h0a; P.h0b = h0b; P.h1a = h1a; P.h1b = h1b;
    P.c0 = c0; P.c1 = c1;
    P.xfb0 = xfb0; P.xfb1 = xfb1;
    P.out = (float*)d_out;
    P.cnt0 = cnt0; P.cnt1 = cnt1; P.cntp = cntp;
    P.roleCnt = roleCnt; P.arrCnt = arrCnt;

    lstm_persistent<<<256, 256, 0, stream>>>(P);

    (void)in_sizes; (void)n_in; (void)out_size;
}

// Round 7
// 7492.665 us; speedup vs baseline: 2.6697x; 2.6697x over previous
//
#include <hip/hip_runtime.h>
#include <math.h>
#include <stdint.h>

typedef _Float16 f16;
typedef _Float16 f16x8 __attribute__((ext_vector_type(8)));
typedef float f32x4 __attribute__((ext_vector_type(4)));

#define BATCH 1024
#define HD    512
#define TST   100
#define BUFSZ 49152   // 32KB A-tile + 16KB B-tile per kt-chunk

// ---------------- access primitives ----------------
// coherent (sc0 sc1): coherence point; cross-XCD safe, placement-independent.
__device__ __forceinline__ float4 coh_ld_x4(const void* p) {
    float4 v;
    asm volatile("global_load_dwordx4 %0, %1, off sc0 sc1" : "=v"(v) : "v"(p) : "memory");
    return v;
}
// plain cacheable load as asm: keeps ALL staging vmem out of the compiler's
// waitcnt bookkeeping so our counted vmcnt(N) pipeline is the only authority.
__device__ __forceinline__ float4 ld_x4(const void* p) {
    float4 v;
    asm volatile("global_load_dwordx4 %0, %1, off" : "=v"(v) : "v"(p) : "memory");
    return v;
}
__device__ __forceinline__ void coh_store_u32(uint32_t* p, uint32_t v) {
    asm volatile("global_store_dword %0, %1, off sc0 sc1" :: "v"(p), "v"(v) : "memory");
}
__device__ __forceinline__ void coh_store_i32(int* p, int v) {
    asm volatile("global_store_dword %0, %1, off sc0 sc1" :: "v"(p), "v"(v) : "memory");
}
__device__ __forceinline__ int coh_load_i32(const int* p) {
    int v;
    asm volatile("global_load_dword %0, %1, off sc0 sc1\n\ts_waitcnt vmcnt(0)"
                 : "=v"(v) : "v"(p) : "memory");
    return v;
}
__device__ __forceinline__ void drain_vm() {
    asm volatile("s_waitcnt vmcnt(0)" ::: "memory");
    __builtin_amdgcn_sched_barrier(0);
}

// ---------------- setup kernels (unchanged, proven) ----------------
__global__ void split_w(const float* __restrict__ src0, int ksplit,
                        const float* __restrict__ src1, int NKT, f16* __restrict__ out)
{
    int c = blockIdx.x * 256 + threadIdx.x;
    int total = 16 * NKT * 2048;
    if (c >= total) return;
    int u = c & 2047;
    int t2 = c >> 11;          // mt*NKT + kt
    int kt = t2 % NKT;
    int mt = t2 / NKT;
    int line = u >> 4;
    int s = (u & 15) ^ (line & 15);   // content slot at this LDS position
    int plane = s >> 3, o = s & 7;
    int m = mt * 128 + line;
    int row = (m & 3) * HD + (m >> 2);    // original row g*512+hl
    int kb = kt * 64 + o * 8;
    f16 v[8];
    #pragma unroll
    for (int e = 0; e < 8; ++e) {
        int k = kb + e;
        float w = (k < ksplit) ? src0[(size_t)row * ksplit + k]
                               : src1[(size_t)row * HD + (k - ksplit)];
        float w32 = w * 32.0f;
        f16 hi = (f16)w32;
        v[e] = plane ? (f16)((w32 - (float)hi) * 2048.0f) : hi;
    }
    *(f16x8*)(out + (size_t)c * 8) = *(f16x8*)v;
}

__global__ void prep_b4(const float* __restrict__ b, float* __restrict__ bt) {
    int c = blockIdx.x * 256 + threadIdx.x;     // c = hl*4+g
    if (c < 2048) bt[c] = b[(c & 3) * HD + (c >> 2)];
}

__global__ void prep_wih4(const float* __restrict__ W, float* __restrict__ o) {
    int c = blockIdx.x * 256 + threadIdx.x;     // c = hl*16 + g*4 + j
    if (c < 8192) {
        int j = c & 3, g = (c >> 2) & 3, hl = c >> 4;
        o[c] = W[(size_t)(g * HD + hl) * 4 + j];
    }
}

// ---------------- cross-block sync: per-block epoch cells (NO RMW) ----------------
// Cells are 64B apart; group base + block*16 ints. Publish = one coherent store
// (parallel across blocks, no line ownership churn). Wait = wave 0 polls all 16
// cells of up to TWO dependencies in a single vector coherent load + __all.
__device__ __forceinline__ void publish(int* cell, int epoch) {
    drain_vm();          // my wave's data stores (sc1) at coherence point
    __syncthreads();     // all waves drained
    if (threadIdx.x == 0)
        coh_store_i32(cell, epoch);
}

__device__ __forceinline__ void wait2(const int* a, int ta, const int* b, int tb) {
    if (threadIdx.x < 64) {
        const int l = threadIdx.x & 15;
        const bool useB = (threadIdx.x & 16) != 0;   // lanes 16-31 (and 48-63) poll b
        const int* p = (useB ? b : a) + l * 16;
        const int tgt = useB ? tb : ta;
        for (;;) {
            int v = coh_load_i32(p);
            if (__all(v >= tgt)) break;
            __builtin_amdgcn_s_sleep(2);
        }
    }
    __syncthreads();
}

// ---------------- fused LSTM layer-step: counted-vmcnt pipelined staging ----------------
// B coherent loads prefetched 2 chunks deep (ping-pong reg banks), A 1 deep.
// Per chunk: s_waitcnt vmcnt(4) (keep B(k+1) in flight); vmcnt(0) only on last.
template<int NKT, bool RANK4>
__device__ __forceinline__ void layer_step(
    const f16* __restrict__ Wst, const f16* __restrict__ src1, const f16* __restrict__ src2,
    const float* __restrict__ wih4, const float* __restrict__ xin, int xstride,
    const float* __restrict__ bt4, float* __restrict__ cT, f16* __restrict__ hout,
    char* smem, int mt, int nt)
{
    const int tid = threadIdx.x;
    const int lane = tid & 63;
    const int wv = tid >> 6;            // wave 0..3
    const int wm = wv & 1, wn = wv >> 1;
    const int l15 = lane & 15, j = lane >> 4;
    const int n0 = nt * 64;

    const int q = (j ^ l15) << 4;
    int ALr[4], BLb[2];
    #pragma unroll
    for (int f = 0; f < 4; ++f) ALr[f] = (wm * 64 + f * 16 + l15) * 256;
    #pragma unroll
    for (int fn = 0; fn < 2; ++fn) BLb[fn] = 32768 + (wn * 32 + fn * 16 + l15) * 256;

    float4 ra[8], rb0[4], rb1[4], xv[2];

    auto issueA = [&](int kt) {
        const f16* ga = Wst + ((size_t)mt * NKT + kt) * 2048 * 8;
        #pragma unroll
        for (int i = 0; i < 8; ++i)
            ra[i] = ld_x4(ga + (size_t)(i * 256 + tid) * 8);
    };
    auto issueB = [&](int kt, float4 (&rb)[4]) {
        #pragma unroll
        for (int i = 0; i < 4; ++i) {
            int v = i * 256 + tid;
            int line = v >> 4;
            int s = (v & 15) ^ (line & 15);
            int ks = kt * 64 + (s & 7) * 8;
            const f16* sp = src1; int kl = ks;
            if (NKT == 16 && ks >= 512) { sp = src2; kl = ks - 512; }
            rb[i] = coh_ld_x4(sp + (size_t)(n0 + line) * 1024 + (s >> 3) * 512 + kl);
        }
    };

    f32x4 accA[4][2] = {};
    f32x4 accB[4][2] = {};

    auto step = [&](int kt, float4 (&rb)[4], bool last) {
        char* buf = smem + (kt & 1) * BUFSZ;
        if (last) asm volatile("s_waitcnt vmcnt(0)" ::: "memory");
        else      asm volatile("s_waitcnt vmcnt(4)" ::: "memory");
        __builtin_amdgcn_sched_barrier(0);
        #pragma unroll
        for (int i = 0; i < 8; ++i) *(float4*)(buf + (i * 256 + tid) * 16) = ra[i];
        #pragma unroll
        for (int i = 0; i < 4; ++i) *(float4*)(buf + 32768 + (i * 256 + tid) * 16) = rb[i];
        if (kt + 1 < NKT) issueA(kt + 1);
        if (kt + 2 < NKT) issueB(kt + 2, rb);   // same parity bank, just consumed
        __syncthreads();
        #pragma unroll
        for (int i = 0; i < 2; ++i) {
            const int off = (i << 6) ^ q;
            f16x8 ah[4], al[4], bh[2], bl[2];
            #pragma unroll
            for (int f = 0; f < 4; ++f) {
                ah[f] = *(const f16x8*)(buf + ALr[f] + off);
                al[f] = *(const f16x8*)(buf + ALr[f] + (off ^ 0x80));
            }
            #pragma unroll
            for (int fn = 0; fn < 2; ++fn) {
                bh[fn] = *(const f16x8*)(buf + BLb[fn] + off);
                bl[fn] = *(const f16x8*)(buf + BLb[fn] + (off ^ 0x80));
            }
            #pragma unroll
            for (int f = 0; f < 4; ++f)
                #pragma unroll
                for (int fn = 0; fn < 2; ++fn) {
                    accA[f][fn] = __builtin_amdgcn_mfma_f32_16x16x32_f16(ah[f], bh[fn], accA[f][fn], 0, 0, 0);
                    accB[f][fn] = __builtin_amdgcn_mfma_f32_16x16x32_f16(al[f], bh[fn], accB[f][fn], 0, 0, 0);
                    accB[f][fn] = __builtin_amdgcn_mfma_f32_16x16x32_f16(ah[f], bl[fn], accB[f][fn], 0, 0, 0);
                }
        }
    };

    // prologue: oldest-first so counted waits retire them early
    if (RANK4) {
        #pragma unroll
        for (int fn = 0; fn < 2; ++fn) {
            const int n = n0 + wn * 32 + fn * 16 + l15;
            xv[fn] = coh_ld_x4(xin + (size_t)n * xstride);
        }
    }
    issueB(0, rb0);
    issueA(0);
    issueB(1, rb1);

    for (int kt = 0; kt < NKT; kt += 2) {
        step(kt,     rb0, false);
        step(kt + 1, rb1, kt + 2 == NKT);
    }

    // epilogue: cell update in registers (D regs r=0..3 are gates i,f,g,o of one hl)
    const float sA = 1.0f / 1024.0f;
    const float sB = 1.0f / (1024.0f * 2048.0f);

    uint32_t* htile = (uint32_t*)smem;   // buf0 region; last compute used buf1
    #pragma unroll
    for (int f = 0; f < 4; ++f) {
        const int hl_loc = wm * 16 + f * 4 + j;
        const int hl = mt * 32 + hl_loc;
        const float4 bv = *(const float4*)(bt4 + hl * 4);
        #pragma unroll
        for (int fn = 0; fn < 2; ++fn) {
            const int n_loc = wn * 32 + fn * 16 + l15;
            const int n = n0 + n_loc;
            float g0 = accA[f][fn][0] * sA + accB[f][fn][0] * sB + bv.x;
            float g1 = accA[f][fn][1] * sA + accB[f][fn][1] * sB + bv.y;
            float g2 = accA[f][fn][2] * sA + accB[f][fn][2] * sB + bv.z;
            float g3 = accA[f][fn][3] * sA + accB[f][fn][3] * sB + bv.w;
            if (RANK4) {
                const float4* wr = (const float4*)(wih4 + hl * 16);
                const float4 x4 = xv[fn];
                g0 += wr[0].x * x4.x + wr[0].y * x4.y + wr[0].z * x4.z + wr[0].w * x4.w;
                g1 += wr[1].x * x4.x + wr[1].y * x4.y + wr[1].z * x4.z + wr[1].w * x4.w;
                g2 += wr[2].x * x4.x + wr[2].y * x4.y + wr[2].z * x4.z + wr[2].w * x4.w;
                g3 += wr[3].x * x4.x + wr[3].y * x4.y + wr[3].z * x4.z + wr[3].w * x4.w;
            }
            const size_t co = (size_t)hl * 1024 + n;   // c: block-private, plain cached
            const float cold = cT[co];
            const float si = 1.0f / (1.0f + expf(-g0));
            const float sf = 1.0f / (1.0f + expf(-g1));
            const float so = 1.0f / (1.0f + expf(-g3));
            const float cn = sf * cold + si * tanhf(g2);
            const float hn = so * tanhf(cn);
            cT[co] = cn;
            const float h32 = hn * 32.0f;
            const f16 hi = (f16)h32;
            const f16 lo = (f16)((h32 - (float)hi) * 2048.0f);
            uint32_t pk = ((uint32_t)__builtin_bit_cast(uint16_t, lo) << 16)
                        | (uint32_t)__builtin_bit_cast(uint16_t, hi);
            htile[n_loc * 33 + hl_loc] = pk;
        }
    }
    __syncthreads();
    // writeout: pack pairs of adjacent hidden cols -> u32 coherent stores
    uint32_t* h32out = (uint32_t*)hout;
    #pragma unroll
    for (int i = 0; i < 8; ++i) {
        int u = i * 256 + tid;              // 0..2047
        int n_loc = u >> 5;                 // 0..63
        int r = u & 31;
        int plane = r >> 4;                 // 0=hi, 1=lo
        int p = r & 15;                     // u32 pair index within tile
        uint32_t t0 = htile[n_loc * 33 + 2 * p];
        uint32_t t1 = htile[n_loc * 33 + 2 * p + 1];
        uint32_t w = plane ? ((t1 & 0xffff0000u) | (t0 >> 16))
                           : ((t1 << 16) | (t0 & 0xffffu));
        coh_store_u32(h32out + (size_t)(n0 + n_loc) * 512 + plane * 256 + mt * 16 + p, w);
    }
}

// ---------------- pred + softmax, 4 batch rows per block (wave w -> row w) ----------------
__device__ __forceinline__ void pred_step(
    const f16* __restrict__ h1, const float* __restrict__ Wp, const float* __restrict__ bp,
    float* __restrict__ outp, float* __restrict__ xfb, int t, int mt, int nt)
{
    const int lane = threadIdx.x & 63;
    const int wv = threadIdx.x >> 6;
    const int n = nt * 64 + mt * 4 + wv;
    const f16* hr = h1 + (size_t)n * 1024;
    const int k0 = lane * 8;
    float4 hv4 = coh_ld_x4(hr + k0);
    float4 lv4 = coh_ld_x4(hr + 512 + k0);
    drain_vm();
    f16x8 hv = __builtin_bit_cast(f16x8, hv4);
    f16x8 lv = __builtin_bit_cast(f16x8, lv4);
    float h[8];
    #pragma unroll
    for (int e = 0; e < 8; ++e)
        h[e] = (float)hv[e] * 0.03125f + (float)lv[e] * (1.0f / 65536.0f);
    float a[4] = {};
    #pragma unroll
    for (int g = 0; g < 4; ++g) {
        const float4 wa = *(const float4*)(Wp + g * HD + k0);
        const float4 wb = *(const float4*)(Wp + g * HD + k0 + 4);
        a[g] = h[0]*wa.x + h[1]*wa.y + h[2]*wa.z + h[3]*wa.w
             + h[4]*wb.x + h[5]*wb.y + h[6]*wb.z + h[7]*wb.w;
    }
    #pragma unroll
    for (int off = 32; off > 0; off >>= 1) {
        a[0] += __shfl_xor(a[0], off);
        a[1] += __shfl_xor(a[1], off);
        a[2] += __shfl_xor(a[2], off);
        a[3] += __shfl_xor(a[3], off);
    }
    if (lane == 0) {
        const float4 bv = *(const float4*)bp;
        float v0 = a[0] + bv.x, v1 = a[1] + bv.y, v2 = a[2] + bv.z, v3 = a[3] + bv.w;
        float* op = outp + (size_t)n * (TST * 4) + t * 4;
        op[0] = v0; op[1] = v1; op[2] = v2; op[3] = v3;   // out: host-read, plain
        float m = fmaxf(fmaxf(v0, v1), fmaxf(v2, v3));
        float e0 = expf(v0 - m), e1 = expf(v1 - m), e2 = expf(v2 - m), e3 = expf(v3 - m);
        float inv = 1.0f / (e0 + e1 + e2 + e3);
        uint32_t* xp = (uint32_t*)(xfb + n * 4);
        float s0 = e0 * inv, s1 = e1 * inv, s2 = e2 * inv, s3 = e3 * inv;
        coh_store_u32(xp + 0, __builtin_bit_cast(uint32_t, s0));
        coh_store_u32(xp + 1, __builtin_bit_cast(uint32_t, s1));
        coh_store_u32(xp + 2, __builtin_bit_cast(uint32_t, s2));
        coh_store_u32(xp + 3, __builtin_bit_cast(uint32_t, s3));
    }
}

// ---------------- persistent whole-network kernel ----------------
struct Params {
    const f16 *WE0, *WE1, *WD0, *WD1;
    const float *wih4E, *wih4D, *btE0, *btE1, *btD0, *btD1;
    const float *X, *Wp, *bp;
    f16 *h0a, *h0b, *h1a, *h1b;
    float *c0, *c1;
    float *xfb0, *xfb1;
    float *out;
    int *f0, *f1, *fp;   // per-block epoch cells: [16 groups][16 blocks x 16 ints]
};

__launch_bounds__(256, 1) __global__ void lstm_persistent(Params P)
{
    __shared__ __align__(16) char smem[2 * BUFSZ];
    const int bx = blockIdx.x;
    const int mt = ((bx & 7) << 1) | ((bx >> 3) & 1);  // 0..15 (weights L2-resident per XCD)
    const int nt = bx >> 4;                            // 0..15 (batch-column group)
    int* f0g = P.f0 + nt * 256;
    int* f1g = P.f1 + nt * 256;
    int* fpg = P.fp + nt * 256;
    int* my0 = f0g + mt * 16;
    int* my1 = f1g + mt * 16;
    int* myp = fpg + mt * 16;
    f16* h0b_[2] = { P.h0a, P.h0b };
    f16* h1b_[2] = { P.h1a, P.h1b };
    float* xfb_[2] = { P.xfb0, P.xfb1 };

    for (int u = 0; u < 2 * TST; ++u) {
        const bool enc = (u < TST);
        const int t = enc ? u : u - TST;

        // ---- layer 0 ---- (flag0 >= u: group's l0(u-1) done -> h0 prev published; WAR-safe)
        if (enc) wait2(f0g, u, f0g, u);
        else     wait2(f0g, u, fpg, t);    // + xfb(t-1) ready
        layer_step<8, true>(enc ? P.WE0 : P.WD0,
                            h0b_[(u + 1) & 1], nullptr,
                            enc ? P.wih4E : P.wih4D,
                            enc ? (P.X + t * 4) : xfb_[(t + 1) & 1],
                            enc ? (TST * 4) : 4,
                            enc ? P.btE0 : P.btD0,
                            P.c0, h0b_[u & 1], smem, mt, nt);
        publish(my0, u + 1);

        // ---- layer 1 ---- (h0(u) ready AND h1(u-1) ready)
        wait2(f0g, u + 1, f1g, u);
        layer_step<16, false>(enc ? P.WE1 : P.WD1,
                              h0b_[u & 1], h1b_[(u + 1) & 1],
                              nullptr, nullptr, 0,
                              enc ? P.btE1 : P.btD1,
                              P.c1, h1b_[u & 1], smem, mt, nt);
        publish(my1, u + 1);

        // ---- pred + softmax feedback (decoder only) ----
        if (!enc) {
            wait2(f1g, u + 1, f1g, u + 1);   // full h1(t) rows from group
            pred_step(h1b_[u & 1], P.Wp, P.bp, P.out, xfb_[t & 1], t, mt, nt);
            publish(myp, t + 1);
        }
    }
}

// ---------------- host ----------------
extern "C" void kernel_launch(void* const* d_in, const int* in_sizes, int n_in,
                              void* d_out, int out_size, void* d_ws, size_t ws_size,
                              hipStream_t stream)
{
    const float* X     = (const float*)d_in[0];
    const float* eWih0 = (const float*)d_in[2];
    const float* eWhh0 = (const float*)d_in[3];
    const float* eb0   = (const float*)d_in[4];
    const float* eWih1 = (const float*)d_in[5];
    const float* eWhh1 = (const float*)d_in[6];
    const float* eb1   = (const float*)d_in[7];
    const float* dWih0 = (const float*)d_in[8];
    const float* dWhh0 = (const float*)d_in[9];
    const float* db0   = (const float*)d_in[10];
    const float* dWih1 = (const float*)d_in[11];
    const float* dWhh1 = (const float*)d_in[12];
    const float* db1   = (const float*)d_in[13];
    const float* Wp    = (const float*)d_in[14];
    const float* bp    = (const float*)d_in[15];

    char* ws = (char*)d_ws;
    size_t off = 0;
    auto alloc = [&](size_t bytes) { char* p = ws + off; off += (bytes + 255) & ~(size_t)255; return p; };
    f16* WE0 = (f16*)alloc((size_t)16 * 8  * 2048 * 16);
    f16* WE1 = (f16*)alloc((size_t)16 * 16 * 2048 * 16);
    f16* WD0 = (f16*)alloc((size_t)16 * 8  * 2048 * 16);
    f16* WD1 = (f16*)alloc((size_t)16 * 16 * 2048 * 16);
    float* wih4E = (float*)alloc(8192 * 4);
    float* wih4D = (float*)alloc(8192 * 4);
    float* btE0 = (float*)alloc(2048 * 4);
    float* btE1 = (float*)alloc(2048 * 4);
    float* btD0 = (float*)alloc(2048 * 4);
    float* btD1 = (float*)alloc(2048 * 4);
    f16* h0a = (f16*)alloc((size_t)BATCH * 1024 * 2);
    f16* h0b = (f16*)alloc((size_t)BATCH * 1024 * 2);
    f16* h1a = (f16*)alloc((size_t)BATCH * 1024 * 2);
    f16* h1b = (f16*)alloc((size_t)BATCH * 1024 * 2);
    float* c0  = (float*)alloc((size_t)HD * BATCH * 4);
    float* c1  = (float*)alloc((size_t)HD * BATCH * 4);
    float* xfb0 = (float*)alloc((size_t)BATCH * 4 * 4);
    float* xfb1 = (float*)alloc((size_t)BATCH * 4 * 4);
    int* f0 = (int*)alloc(16 * 256 * 4);
    int* f1 = (int*)alloc(16 * 256 * 4);
    int* fp = (int*)alloc(16 * 256 * 4);
    if (off > ws_size) return;   // workspace too small -> loud failure

    // one-time (per-call) weight prep
    split_w<<<(16 * 8  * 2048) / 256, 256, 0, stream>>>(nullptr, 0,   eWhh0, 8,  WE0);
    split_w<<<(16 * 16 * 2048) / 256, 256, 0, stream>>>(eWih1, 512, eWhh1, 16, WE1);
    split_w<<<(16 * 8  * 2048) / 256, 256, 0, stream>>>(nullptr, 0,   dWhh0, 8,  WD0);
    split_w<<<(16 * 16 * 2048) / 256, 256, 0, stream>>>(dWih1, 512, dWhh1, 16, WD1);
    prep_wih4<<<32, 256, 0, stream>>>(eWih0, wih4E);
    prep_wih4<<<32, 256, 0, stream>>>(dWih0, wih4D);
    prep_b4<<<8, 256, 0, stream>>>(eb0, btE0);
    prep_b4<<<8, 256, 0, stream>>>(eb1, btE1);
    prep_b4<<<8, 256, 0, stream>>>(db0, btD0);
    prep_b4<<<8, 256, 0, stream>>>(db1, btD1);

    hipMemsetAsync(h0b, 0, (size_t)BATCH * 1024 * 2, stream);   // h0 parity-1 (read at u=0)
    hipMemsetAsync(h1b, 0, (size_t)BATCH * 1024 * 2, stream);   // h1 parity-1
    hipMemsetAsync(c0, 0, (size_t)HD * BATCH * 4, stream);
    hipMemsetAsync(c1, 0, (size_t)HD * BATCH * 4, stream);
    hipMemsetAsync(xfb1, 0, (size_t)BATCH * 4 * 4, stream);     // x feedback at dec t=0
    hipMemsetAsync(f0, 0, 16 * 256 * 4, stream);
    hipMemsetAsync(f1, 0, 16 * 256 * 4, stream);
    hipMemsetAsync(fp, 0, 16 * 256 * 4, stream);

    Params P;
    P.WE0 = WE0; P.WE1 = WE1; P.WD0 = WD0; P.WD1 = WD1;
    P.wih4E = wih4E; P.wih4D = wih4D;
    P.btE0 = btE0; P.btE1 = btE1; P.btD0 = btD0; P.btD1 = btD1;
    P.X = X; P.Wp = Wp; P.bp = bp;
    P.h0a = h0a; P.h0b = h0b; P.h1a = h1a; P.h1b = h1b;
    P.c0 = c0; P.c1 = c1;
    P.xfb0 = xfb0; P.xfb1 = xfb1;
    P.out = (float*)d_out;
    P.f0 = f0; P.f1 = f1; P.fp = fp;

    lstm_persistent<<<256, 256, 0, stream>>>(P);

    (void)in_sizes; (void)n_in; (void)out_size;
}

// Round 8
// 7381.899 us; speedup vs baseline: 2.7098x; 1.0150x over previous
//
#include <hip/hip_runtime.h>
#include <math.h>
#include <stdint.h>

typedef _Float16 f16;
typedef _Float16 f16x8 __attribute__((ext_vector_type(8)));
typedef float f32x4 __attribute__((ext_vector_type(4)));

#define BATCH 1024
#define HD    512
#define TST   100
#define BUFSZ 49152   // 32KB A-tile + 16KB B-tile per kt-chunk

// ---------------- access primitives ----------------
__device__ __forceinline__ float4 coh_ld_x4(const void* p) {
    float4 v;
    asm volatile("global_load_dwordx4 %0, %1, off sc0 sc1" : "=v"(v) : "v"(p) : "memory");
    return v;
}
__device__ __forceinline__ float4 ld_x4(const void* p) {
    float4 v;
    asm volatile("global_load_dwordx4 %0, %1, off" : "=v"(v) : "v"(p) : "memory");
    return v;
}
__device__ __forceinline__ void coh_store_u32(uint32_t* p, uint32_t v) {
    asm volatile("global_store_dword %0, %1, off sc0 sc1" :: "v"(p), "v"(v) : "memory");
}
__device__ __forceinline__ void coh_store_i32(int* p, int v) {
    asm volatile("global_store_dword %0, %1, off sc0 sc1" :: "v"(p), "v"(v) : "memory");
}
__device__ __forceinline__ int coh_load_i32(const int* p) {
    int v;
    asm volatile("global_load_dword %0, %1, off sc0 sc1\n\ts_waitcnt vmcnt(0)"
                 : "=v"(v) : "v"(p) : "memory");
    return v;
}
__device__ __forceinline__ void drain_vm() {
    asm volatile("s_waitcnt vmcnt(0)" ::: "memory");
    __builtin_amdgcn_sched_barrier(0);
}
// counted wait; n is compile-time constant after full unroll -> switch folds
__device__ __forceinline__ void wait_vm(int n) {
    switch (n) {
    case 0:  asm volatile("s_waitcnt vmcnt(0)"  ::: "memory"); break;
    case 8:  asm volatile("s_waitcnt vmcnt(8)"  ::: "memory"); break;
    case 12: asm volatile("s_waitcnt vmcnt(12)" ::: "memory"); break;
    case 16: asm volatile("s_waitcnt vmcnt(16)" ::: "memory"); break;
    default: asm volatile("s_waitcnt vmcnt(20)" ::: "memory"); break;
    }
    __builtin_amdgcn_sched_barrier(0);
}

// fast transcendentals (absolute error ~2^-22, monitored via absmax)
__device__ __forceinline__ float fast_sig(float x) {
    return 1.0f / (1.0f + __expf(-x));
}
__device__ __forceinline__ float fast_tanh(float x) {
    float xc = fminf(fmaxf(x, -15.0f), 15.0f);
    float e = __expf(2.0f * xc);
    return 1.0f - 2.0f / (e + 1.0f);
}

// ---------------- setup kernels (unchanged, proven) ----------------
__global__ void split_w(const float* __restrict__ src0, int ksplit,
                        const float* __restrict__ src1, int NKT, f16* __restrict__ out)
{
    int c = blockIdx.x * 256 + threadIdx.x;
    int total = 16 * NKT * 2048;
    if (c >= total) return;
    int u = c & 2047;
    int t2 = c >> 11;          // mt*NKT + kt
    int kt = t2 % NKT;
    int mt = t2 / NKT;
    int line = u >> 4;
    int s = (u & 15) ^ (line & 15);   // content slot at this LDS position
    int plane = s >> 3, o = s & 7;
    int m = mt * 128 + line;
    int row = (m & 3) * HD + (m >> 2);    // original row g*512+hl
    int kb = kt * 64 + o * 8;
    f16 v[8];
    #pragma unroll
    for (int e = 0; e < 8; ++e) {
        int k = kb + e;
        float w = (k < ksplit) ? src0[(size_t)row * ksplit + k]
                               : src1[(size_t)row * HD + (k - ksplit)];
        float w32 = w * 32.0f;
        f16 hi = (f16)w32;
        v[e] = plane ? (f16)((w32 - (float)hi) * 2048.0f) : hi;
    }
    *(f16x8*)(out + (size_t)c * 8) = *(f16x8*)v;
}

__global__ void prep_b4(const float* __restrict__ b, float* __restrict__ bt) {
    int c = blockIdx.x * 256 + threadIdx.x;     // c = hl*4+g
    if (c < 2048) bt[c] = b[(c & 3) * HD + (c >> 2)];
}

__global__ void prep_wih4(const float* __restrict__ W, float* __restrict__ o) {
    int c = blockIdx.x * 256 + threadIdx.x;     // c = hl*16 + g*4 + j
    if (c < 8192) {
        int j = c & 3, g = (c >> 2) & 3, hl = c >> 4;
        o[c] = W[(size_t)(g * HD + hl) * 4 + j];
    }
}

// ---------------- cross-block sync: per-block epoch cells (NO RMW) ----------------
__device__ __forceinline__ void publish(int* cell, int epoch) {
    drain_vm();
    __syncthreads();
    if (threadIdx.x == 0)
        coh_store_i32(cell, epoch);
}

__device__ __forceinline__ void wait2(const int* a, int ta, const int* b, int tb) {
    if (threadIdx.x < 64) {
        const int l = threadIdx.x & 15;
        const bool useB = (threadIdx.x & 16) != 0;
        const int* p = (useB ? b : a) + l * 16;
        const int tgt = useB ? tb : ta;
        for (;;) {
            int v = coh_load_i32(p);
            if (__all(v >= tgt)) break;
            __builtin_amdgcn_s_sleep(2);
        }
    }
    __syncthreads();
}

// ---------------- fused LSTM layer-step: depth-4 B / depth-2 A pipeline ----------------
template<int NKT, bool RANK4>
__device__ __forceinline__ void layer_step(
    const f16* __restrict__ Wst, const f16* __restrict__ src1, const f16* __restrict__ src2,
    const float* __restrict__ wih4, const float* __restrict__ xin, int xstride,
    const float* __restrict__ bt4, float* __restrict__ cT, f16* __restrict__ hout,
    char* smem, int mt, int nt)
{
    const int tid = threadIdx.x;
    const int lane = tid & 63;
    const int wv = tid >> 6;            // wave 0..3
    const int wm = wv & 1, wn = wv >> 1;
    const int l15 = lane & 15, j = lane >> 4;
    const int n0 = nt * 64;

    const int q = (j ^ l15) << 4;
    int ALr[4], BLb[2];
    #pragma unroll
    for (int f = 0; f < 4; ++f) ALr[f] = (wm * 64 + f * 16 + l15) * 256;
    #pragma unroll
    for (int fn = 0; fn < 2; ++fn) BLb[fn] = 32768 + (wn * 32 + fn * 16 + l15) * 256;

    float4 rak[2][8];   // A register banks (depth 2)
    float4 rbk[4][4];   // B register banks (depth 4)
    float4 xv[2];

    auto issueA = [&](int kt, int bank) {
        const f16* ga = Wst + ((size_t)mt * NKT + kt) * 2048 * 8;
        #pragma unroll
        for (int i = 0; i < 8; ++i)
            rak[bank][i] = ld_x4(ga + (size_t)(i * 256 + tid) * 8);
    };
    auto issueB = [&](int kt, int bank) {
        #pragma unroll
        for (int i = 0; i < 4; ++i) {
            int v = i * 256 + tid;
            int line = v >> 4;
            int s = (v & 15) ^ (line & 15);
            int ks = kt * 64 + (s & 7) * 8;
            const f16* sp = src1; int kl = ks;
            if (NKT == 16 && ks >= 512) { sp = src2; kl = ks - 512; }
            rbk[bank][i] = coh_ld_x4(sp + (size_t)(n0 + line) * 1024 + (s >> 3) * 512 + kl);
        }
    };

    f32x4 accA[4][2] = {};
    f32x4 accB[4][2] = {};

    // prologue (issue order defines the vmcnt queue — do not reorder)
    if (RANK4) {
        #pragma unroll
        for (int fn = 0; fn < 2; ++fn) {
            const int n = n0 + wn * 32 + fn * 16 + l15;
            xv[fn] = coh_ld_x4(xin + (size_t)n * xstride);
        }
    }
    issueB(0, 0); issueA(0, 0); issueB(1, 1); issueA(1, 1); issueB(2, 2); issueB(3, 3);

    #pragma unroll
    for (int kt = 0; kt < NKT; ++kt) {
        char* buf = smem + (kt & 1) * BUFSZ;
        // instrs newer than needed A(kt) in the queue (derived; see round notes):
        const int wcnt = (kt == NKT - 1) ? 0 : (kt == NKT - 2) ? 8 :
                         (kt == NKT - 3) ? 12 : (kt <= 1) ? 20 : 16;
        wait_vm(wcnt);
        #pragma unroll
        for (int i = 0; i < 8; ++i) *(float4*)(buf + (i * 256 + tid) * 16) = rak[kt & 1][i];
        #pragma unroll
        for (int i = 0; i < 4; ++i) *(float4*)(buf + 32768 + (i * 256 + tid) * 16) = rbk[kt & 3][i];
        if (kt + 2 < NKT) issueA(kt + 2, kt & 1);     // refill bank just consumed
        if (kt + 4 < NKT) issueB(kt + 4, kt & 3);
        __syncthreads();
        #pragma unroll
        for (int i = 0; i < 2; ++i) {
            const int off = (i << 6) ^ q;
            f16x8 ah[4], al[4], bh[2], bl[2];
            #pragma unroll
            for (int f = 0; f < 4; ++f) {
                ah[f] = *(const f16x8*)(buf + ALr[f] + off);
                al[f] = *(const f16x8*)(buf + ALr[f] + (off ^ 0x80));
            }
            #pragma unroll
            for (int fn = 0; fn < 2; ++fn) {
                bh[fn] = *(const f16x8*)(buf + BLb[fn] + off);
                bl[fn] = *(const f16x8*)(buf + BLb[fn] + (off ^ 0x80));
            }
            #pragma unroll
            for (int f = 0; f < 4; ++f)
                #pragma unroll
                for (int fn = 0; fn < 2; ++fn) {
                    accA[f][fn] = __builtin_amdgcn_mfma_f32_16x16x32_f16(ah[f], bh[fn], accA[f][fn], 0, 0, 0);
                    accB[f][fn] = __builtin_amdgcn_mfma_f32_16x16x32_f16(al[f], bh[fn], accB[f][fn], 0, 0, 0);
                    accB[f][fn] = __builtin_amdgcn_mfma_f32_16x16x32_f16(ah[f], bl[fn], accB[f][fn], 0, 0, 0);
                }
        }
    }

    // epilogue: cell update in registers (D regs r=0..3 are gates i,f,g,o of one hl)
    const float sA = 1.0f / 1024.0f;
    const float sB = 1.0f / (1024.0f * 2048.0f);

    uint32_t* htile = (uint32_t*)smem;   // buf0 region; last compute used buf1 (NKT even)
    #pragma unroll
    for (int f = 0; f < 4; ++f) {
        const int hl_loc = wm * 16 + f * 4 + j;
        const int hl = mt * 32 + hl_loc;
        const float4 bv = *(const float4*)(bt4 + hl * 4);
        #pragma unroll
        for (int fn = 0; fn < 2; ++fn) {
            const int n_loc = wn * 32 + fn * 16 + l15;
            const int n = n0 + n_loc;
            float g0 = accA[f][fn][0] * sA + accB[f][fn][0] * sB + bv.x;
            float g1 = accA[f][fn][1] * sA + accB[f][fn][1] * sB + bv.y;
            float g2 = accA[f][fn][2] * sA + accB[f][fn][2] * sB + bv.z;
            float g3 = accA[f][fn][3] * sA + accB[f][fn][3] * sB + bv.w;
            if (RANK4) {
                const float4* wr = (const float4*)(wih4 + hl * 16);
                const float4 x4 = xv[fn];
                g0 += wr[0].x * x4.x + wr[0].y * x4.y + wr[0].z * x4.z + wr[0].w * x4.w;
                g1 += wr[1].x * x4.x + wr[1].y * x4.y + wr[1].z * x4.z + wr[1].w * x4.w;
                g2 += wr[2].x * x4.x + wr[2].y * x4.y + wr[2].z * x4.z + wr[2].w * x4.w;
                g3 += wr[3].x * x4.x + wr[3].y * x4.y + wr[3].z * x4.z + wr[3].w * x4.w;
            }
            const size_t co = (size_t)hl * 1024 + n;   // c: block-private, plain cached
            const float cold = cT[co];
            const float si = fast_sig(g0);
            const float sf = fast_sig(g1);
            const float so = fast_sig(g3);
            const float cn = sf * cold + si * fast_tanh(g2);
            const float hn = so * fast_tanh(cn);
            cT[co] = cn;
            const float h32 = hn * 32.0f;
            const f16 hi = (f16)h32;
            const f16 lo = (f16)((h32 - (float)hi) * 2048.0f);
            uint32_t pk = ((uint32_t)__builtin_bit_cast(uint16_t, lo) << 16)
                        | (uint32_t)__builtin_bit_cast(uint16_t, hi);
            htile[n_loc * 33 + hl_loc] = pk;
        }
    }
    __syncthreads();
    uint32_t* h32out = (uint32_t*)hout;
    #pragma unroll
    for (int i = 0; i < 8; ++i) {
        int u = i * 256 + tid;              // 0..2047
        int n_loc = u >> 5;                 // 0..63
        int r = u & 31;
        int plane = r >> 4;                 // 0=hi, 1=lo
        int p = r & 15;                     // u32 pair index within tile
        uint32_t t0 = htile[n_loc * 33 + 2 * p];
        uint32_t t1 = htile[n_loc * 33 + 2 * p + 1];
        uint32_t w = plane ? ((t1 & 0xffff0000u) | (t0 >> 16))
                           : ((t1 << 16) | (t0 & 0xffffu));
        coh_store_u32(h32out + (size_t)(n0 + n_loc) * 512 + plane * 256 + mt * 16 + p, w);
    }
}

// ---------------- pred + softmax, 4 batch rows per block (wave w -> row w) ----------------
__device__ __forceinline__ void pred_step(
    const f16* __restrict__ h1, const float* __restrict__ Wp, const float* __restrict__ bp,
    float* __restrict__ outp, float* __restrict__ xfb, int t, int mt, int nt)
{
    const int lane = threadIdx.x & 63;
    const int wv = threadIdx.x >> 6;
    const int n = nt * 64 + mt * 4 + wv;
    const f16* hr = h1 + (size_t)n * 1024;
    const int k0 = lane * 8;
    float4 hv4 = coh_ld_x4(hr + k0);
    float4 lv4 = coh_ld_x4(hr + 512 + k0);
    drain_vm();
    f16x8 hv = __builtin_bit_cast(f16x8, hv4);
    f16x8 lv = __builtin_bit_cast(f16x8, lv4);
    float h[8];
    #pragma unroll
    for (int e = 0; e < 8; ++e)
        h[e] = (float)hv[e] * 0.03125f + (float)lv[e] * (1.0f / 65536.0f);
    float a[4] = {};
    #pragma unroll
    for (int g = 0; g < 4; ++g) {
        const float4 wa = *(const float4*)(Wp + g * HD + k0);
        const float4 wb = *(const float4*)(Wp + g * HD + k0 + 4);
        a[g] = h[0]*wa.x + h[1]*wa.y + h[2]*wa.z + h[3]*wa.w
             + h[4]*wb.x + h[5]*wb.y + h[6]*wb.z + h[7]*wb.w;
    }
    #pragma unroll
    for (int off = 32; off > 0; off >>= 1) {
        a[0] += __shfl_xor(a[0], off);
        a[1] += __shfl_xor(a[1], off);
        a[2] += __shfl_xor(a[2], off);
        a[3] += __shfl_xor(a[3], off);
    }
    if (lane == 0) {
        const float4 bv = *(const float4*)bp;
        float v0 = a[0] + bv.x, v1 = a[1] + bv.y, v2 = a[2] + bv.z, v3 = a[3] + bv.w;
        float* op = outp + (size_t)n * (TST * 4) + t * 4;
        op[0] = v0; op[1] = v1; op[2] = v2; op[3] = v3;
        float m = fmaxf(fmaxf(v0, v1), fmaxf(v2, v3));
        float e0 = expf(v0 - m), e1 = expf(v1 - m), e2 = expf(v2 - m), e3 = expf(v3 - m);
        float inv = 1.0f / (e0 + e1 + e2 + e3);
        uint32_t* xp = (uint32_t*)(xfb + n * 4);
        float s0 = e0 * inv, s1 = e1 * inv, s2 = e2 * inv, s3 = e3 * inv;
        coh_store_u32(xp + 0, __builtin_bit_cast(uint32_t, s0));
        coh_store_u32(xp + 1, __builtin_bit_cast(uint32_t, s1));
        coh_store_u32(xp + 2, __builtin_bit_cast(uint32_t, s2));
        coh_store_u32(xp + 3, __builtin_bit_cast(uint32_t, s3));
    }
}

// ---------------- persistent whole-network kernel ----------------
struct Params {
    const f16 *WE0, *WE1, *WD0, *WD1;
    const float *wih4E, *wih4D, *btE0, *btE1, *btD0, *btD1;
    const float *X, *Wp, *bp;
    f16 *h0a, *h0b, *h1a, *h1b;
    float *c0, *c1;
    float *xfb0, *xfb1;
    float *out;
    int *f0, *f1, *fp;   // per-block epoch cells: [16 groups][16 blocks x 16 ints]
};

__launch_bounds__(256, 1) __global__ void lstm_persistent(Params P)
{
    __shared__ __align__(16) char smem[2 * BUFSZ];
    const int bx = blockIdx.x;
    const int mt = ((bx & 7) << 1) | ((bx >> 3) & 1);  // 0..15 (weights L2-resident per XCD)
    const int nt = bx >> 4;                            // 0..15 (batch-column group)
    int* f0g = P.f0 + nt * 256;
    int* f1g = P.f1 + nt * 256;
    int* fpg = P.fp + nt * 256;
    int* my0 = f0g + mt * 16;
    int* my1 = f1g + mt * 16;
    int* myp = fpg + mt * 16;
    f16* h0b_[2] = { P.h0a, P.h0b };
    f16* h1b_[2] = { P.h1a, P.h1b };
    float* xfb_[2] = { P.xfb0, P.xfb1 };

    for (int u = 0; u < 2 * TST; ++u) {
        const bool enc = (u < TST);
        const int t = enc ? u : u - TST;

        // ---- layer 0 ---- (f0 >= u: group's l0(u-1) done; WAR-safe by program order)
        if (enc) wait2(f0g, u, f0g, u);
        else     wait2(f0g, u, fpg, t);    // + xfb(t-1) ready
        layer_step<8, true>(enc ? P.WE0 : P.WD0,
                            h0b_[(u + 1) & 1], nullptr,
                            enc ? P.wih4E : P.wih4D,
                            enc ? (P.X + t * 4) : xfb_[(t + 1) & 1],
                            enc ? (TST * 4) : 4,
                            enc ? P.btE0 : P.btD0,
                            P.c0, h0b_[u & 1], smem, mt, nt);
        publish(my0, u + 1);

        // ---- layer 1 ---- (h0(u) ready AND h1(u-1) ready)
        wait2(f0g, u + 1, f1g, u);
        layer_step<16, false>(enc ? P.WE1 : P.WD1,
                              h0b_[u & 1], h1b_[(u + 1) & 1],
                              nullptr, nullptr, 0,
                              enc ? P.btE1 : P.btD1,
                              P.c1, h1b_[u & 1], smem, mt, nt);
        publish(my1, u + 1);

        // ---- pred + softmax feedback (decoder only) ----
        if (!enc) {
            wait2(f1g, u + 1, f1g, u + 1);   // full h1(t) rows from group
            pred_step(h1b_[u & 1], P.Wp, P.bp, P.out, xfb_[t & 1], t, mt, nt);
            publish(myp, t + 1);
        }
    }
}

// ---------------- host ----------------
extern "C" void kernel_launch(void* const* d_in, const int* in_sizes, int n_in,
                              void* d_out, int out_size, void* d_ws, size_t ws_size,
                              hipStream_t stream)
{
    const float* X     = (const float*)d_in[0];
    const float* eWih0 = (const float*)d_in[2];
    const float* eWhh0 = (const float*)d_in[3];
    const float* eb0   = (const float*)d_in[4];
    const float* eWih1 = (const float*)d_in[5];
    const float* eWhh1 = (const float*)d_in[6];
    const float* eb1   = (const float*)d_in[7];
    const float* dWih0 = (const float*)d_in[8];
    const float* dWhh0 = (const float*)d_in[9];
    const float* db0   = (const float*)d_in[10];
    const float* dWih1 = (const float*)d_in[11];
    const float* dWhh1 = (const float*)d_in[12];
    const float* db1   = (const float*)d_in[13];
    const float* Wp    = (const float*)d_in[14];
    const float* bp    = (const float*)d_in[15];

    char* ws = (char*)d_ws;
    size_t off = 0;
    auto alloc = [&](size_t bytes) { char* p = ws + off; off += (bytes + 255) & ~(size_t)255; return p; };
    f16* WE0 = (f16*)alloc((size_t)16 * 8  * 2048 * 16);
    f16* WE1 = (f16*)alloc((size_t)16 * 16 * 2048 * 16);
    f16* WD0 = (f16*)alloc((size_t)16 * 8  * 2048 * 16);
    f16* WD1 = (f16*)alloc((size_t)16 * 16 * 2048 * 16);
    float* wih4E = (float*)alloc(8192 * 4);
    float* wih4D = (float*)alloc(8192 * 4);
    float* btE0 = (float*)alloc(2048 * 4);
    float* btE1 = (float*)alloc(2048 * 4);
    float* btD0 = (float*)alloc(2048 * 4);
    float* btD1 = (float*)alloc(2048 * 4);
    f16* h0a = (f16*)alloc((size_t)BATCH * 1024 * 2);
    f16* h0b = (f16*)alloc((size_t)BATCH * 1024 * 2);
    f16* h1a = (f16*)alloc((size_t)BATCH * 1024 * 2);
    f16* h1b = (f16*)alloc((size_t)BATCH * 1024 * 2);
    float* c0  = (float*)alloc((size_t)HD * BATCH * 4);
    float* c1  = (float*)alloc((size_t)HD * BATCH * 4);
    float* xfb0 = (float*)alloc((size_t)BATCH * 4 * 4);
    float* xfb1 = (float*)alloc((size_t)BATCH * 4 * 4);
    int* f0 = (int*)alloc(16 * 256 * 4);
    int* f1 = (int*)alloc(16 * 256 * 4);
    int* fp = (int*)alloc(16 * 256 * 4);
    if (off > ws_size) return;   // workspace too small -> loud failure

    // one-time (per-call) weight prep
    split_w<<<(16 * 8  * 2048) / 256, 256, 0, stream>>>(nullptr, 0,   eWhh0, 8,  WE0);
    split_w<<<(16 * 16 * 2048) / 256, 256, 0, stream>>>(eWih1, 512, eWhh1, 16, WE1);
    split_w<<<(16 * 8  * 2048) / 256, 256, 0, stream>>>(nullptr, 0,   dWhh0, 8,  WD0);
    split_w<<<(16 * 16 * 2048) / 256, 256, 0, stream>>>(dWih1, 512, dWhh1, 16, WD1);
    prep_wih4<<<32, 256, 0, stream>>>(eWih0, wih4E);
    prep_wih4<<<32, 256, 0, stream>>>(dWih0, wih4D);
    prep_b4<<<8, 256, 0, stream>>>(eb0, btE0);
    prep_b4<<<8, 256, 0, stream>>>(eb1, btE1);
    prep_b4<<<8, 256, 0, stream>>>(db0, btD0);
    prep_b4<<<8, 256, 0, stream>>>(db1, btD1);

    hipMemsetAsync(h0b, 0, (size_t)BATCH * 1024 * 2, stream);   // h0 parity-1 (read at u=0)
    hipMemsetAsync(h1b, 0, (size_t)BATCH * 1024 * 2, stream);   // h1 parity-1
    hipMemsetAsync(c0, 0, (size_t)HD * BATCH * 4, stream);
    hipMemsetAsync(c1, 0, (size_t)HD * BATCH * 4, stream);
    hipMemsetAsync(xfb1, 0, (size_t)BATCH * 4 * 4, stream);     // x feedback at dec t=0
    hipMemsetAsync(f0, 0, 16 * 256 * 4, stream);
    hipMemsetAsync(f1, 0, 16 * 256 * 4, stream);
    hipMemsetAsync(fp, 0, 16 * 256 * 4, stream);

    Params P;
    P.WE0 = WE0; P.WE1 = WE1; P.WD0 = WD0; P.WD1 = WD1;
    P.wih4E = wih4E; P.wih4D = wih4D;
    P.btE0 = btE0; P.btE1 = btE1; P.btD0 = btD0; P.btD1 = btD1;
    P.X = X; P.Wp = Wp; P.bp = bp;
    P.h0a = h0a; P.h0b = h0b; P.h1a = h1a; P.h1b = h1b;
    P.c0 = c0; P.c1 = c1;
    P.xfb0 = xfb0; P.xfb1 = xfb1;
    P.out = (float*)d_out;
    P.f0 = f0; P.f1 = f1; P.fp = fp;

    lstm_persistent<<<256, 256, 0, stream>>>(P);

    (void)in_sizes; (void)n_in; (void)out_size;
}